// Round 1
// baseline (95.576 us; speedup 1.0000x reference)
//
#include <hip/hip_runtime.h>

#define M_TOTAL 16384
#define N_TOTAL 1024
#define K_TOTAL 1024
#define BM 128
#define BN 128
#define BK 64

using f32x4  = __attribute__((ext_vector_type(4))) float;
using bf16x8 = __attribute__((ext_vector_type(8))) short;
using bf16x4 = __attribute__((ext_vector_type(4))) short;

__device__ __forceinline__ short f2bf(float f) {
    // round-to-nearest-even fp32 -> bf16 (no NaN handling needed; inputs are finite)
    unsigned u = __builtin_bit_cast(unsigned, f);
    u += 0x7fffu + ((u >> 16) & 1u);
    return (short)(u >> 16);
}

// C[m][n] = sum_k X[m][k] * W[n][k] + bias[n]
// X: 16384x1024 fp32 row-major, W: 1024x1024 fp32 row-major (B^T GEMM), C fp32.
__global__ __launch_bounds__(256) void gemm_bias_kernel(
    const float* __restrict__ X, const float* __restrict__ W,
    const float* __restrict__ bias, float* __restrict__ C)
{
    // bf16 tiles, XOR-swizzled: element [row][k] lives at byte
    // (row*128 + k*2) ^ ((row&7)<<4). Breaks the 16-way bank conflict of
    // 128B-stride rows on ds_read_b128 (lanes 0..7 spread over all 32 banks,
    // 2-way aliasing = free).
    __shared__ short As[BM * BK];
    __shared__ short Bs[BN * BK];

    const int tid  = threadIdx.x;
    const int lane = tid & 63;
    const int wave = tid >> 6;
    const int wr = wave >> 1;   // wave row 0..1  (64 rows each)
    const int wc = wave & 1;    // wave col 0..1  (64 cols each)

    const int nbn = N_TOTAL / BN;           // 8
    const int bm = blockIdx.x / nbn;
    const int bn = blockIdx.x % nbn;
    const int m0 = bm * BM, n0 = bn * BN;

    // staging: thread t handles row (t>>4)+16*pass, float4-index t&15
    const int srow  = tid >> 4;   // 0..15
    const int scol4 = tid & 15;   // 0..15  -> k offset scol4*4

    f32x4 acc[4][4] = {};

    char* const Ab = (char*)As;
    char* const Bb = (char*)Bs;

    for (int k0 = 0; k0 < K_TOTAL; k0 += BK) {
        __syncthreads();   // previous iteration's reads done before overwrite
        #pragma unroll
        for (int pass = 0; pass < 8; ++pass) {
            const int row = srow + pass * 16;
            const int off = (row * (BK * 2) + scol4 * 8) ^ ((row & 7) << 4);
            {
                const f32x4 v = *(const f32x4*)(X + (m0 + row) * K_TOTAL + k0 + scol4 * 4);
                bf16x4 b;
                b[0] = f2bf(v[0]); b[1] = f2bf(v[1]); b[2] = f2bf(v[2]); b[3] = f2bf(v[3]);
                *(bf16x4*)(Ab + off) = b;
            }
            {
                const f32x4 v = *(const f32x4*)(W + (n0 + row) * K_TOTAL + k0 + scol4 * 4);
                bf16x4 b;
                b[0] = f2bf(v[0]); b[1] = f2bf(v[1]); b[2] = f2bf(v[2]); b[3] = f2bf(v[3]);
                *(bf16x4*)(Bb + off) = b;
            }
        }
        __syncthreads();

        #pragma unroll
        for (int ks = 0; ks < 2; ++ks) {
            const int kel = ks * 32 + ((lane >> 4) << 3);  // k element base for this lane
            bf16x8 af[4], bfr[4];
            #pragma unroll
            for (int i = 0; i < 4; ++i) {
                const int arow = wr * 64 + i * 16 + (lane & 15);
                af[i]  = *(const bf16x8*)(Ab + ((arow * (BK * 2) + kel * 2) ^ ((arow & 7) << 4)));
                const int brow = wc * 64 + i * 16 + (lane & 15);
                bfr[i] = *(const bf16x8*)(Bb + ((brow * (BK * 2) + kel * 2) ^ ((brow & 7) << 4)));
            }
            #pragma unroll
            for (int mi = 0; mi < 4; ++mi) {
                #pragma unroll
                for (int ni = 0; ni < 4; ++ni) {
                    acc[mi][ni] = __builtin_amdgcn_mfma_f32_16x16x32_bf16(
                        af[mi], bfr[ni], acc[mi][ni], 0, 0, 0);
                }
            }
        }
    }

    // epilogue: D element (row=(lane>>4)*4+r, col=lane&15)  [m89-verified]
    const int cl = lane & 15;
    const int r0 = (lane >> 4) * 4;
    #pragma unroll
    for (int ni = 0; ni < 4; ++ni) {
        const int n = n0 + wc * 64 + ni * 16 + cl;
        const float bvv = bias[n];
        #pragma unroll
        for (int mi = 0; mi < 4; ++mi) {
            const int m = m0 + wr * 64 + mi * 16 + r0;
            #pragma unroll
            for (int r = 0; r < 4; ++r) {
                C[(m + r) * N_TOTAL + n] = acc[mi][ni][r] + bvv;
            }
        }
    }
}

extern "C" void kernel_launch(void* const* d_in, const int* in_sizes, int n_in,
                              void* d_out, int out_size, void* d_ws, size_t ws_size,
                              hipStream_t stream) {
    // inputs: 0:X 1:Wq 2:bq 3:Wk 4:bk 5:Wv 6:bv
    // out = softmax-row-sum (==1) * V  ==  X @ Wv^T + bv
    const float* X  = (const float*)d_in[0];
    const float* Wv = (const float*)d_in[5];
    const float* bv = (const float*)d_in[6];
    float* out = (float*)d_out;

    dim3 grid((M_TOTAL / BM) * (N_TOTAL / BN));   // 128 * 8 = 1024 blocks
    gemm_bias_kernel<<<grid, dim3(256), 0, stream>>>(X, Wv, bv, out);
}